// Round 1
// baseline (1129.853 us; speedup 1.0000x reference)
//
#include <hip/hip_runtime.h>
#include <hip/hip_bf16.h>
#include <math.h>

// ---------------------------------------------------------------------------
// DeepseekV2 MoE: T=16384 tokens, H=1024, E=8 routed (top-2) + 1 shared, I=512
// Strategy: bf16 MFMA (16x16x32) dense over 9 "experts" (shared = expert 8,
// weight 1.0). m97-style 128x128 tiles with global_load_lds width-16 staging.
// ---------------------------------------------------------------------------

#define T_TOTAL 16384
#define HDIM 1024
#define IDIM 512
#define NE 9  // 8 routed + 1 shared

typedef __bf16 bf16x8 __attribute__((ext_vector_type(8)));
typedef float f32x4 __attribute__((ext_vector_type(4)));

typedef __attribute__((address_space(1))) void gvoid_t;
typedef __attribute__((address_space(3))) void lvoid_t;

__device__ __forceinline__ void load_lds16(const void* g, void* l) {
  // 16B per lane, dest = wave-uniform base + lane*16
  __builtin_amdgcn_global_load_lds((const gvoid_t*)g, (lvoid_t*)l, 16, 0, 0);
}

__device__ __forceinline__ f32x4 mfma_bf16(bf16x8 a, bf16x8 b, f32x4 c) {
  return __builtin_amdgcn_mfma_f32_16x16x32_bf16(a, b, c, 0, 0, 0);
}

// ---------------------------------------------------------------------------
// Gate: one wave per token. fp32 logits -> softmax -> top2 -> normalized
// combine weights cw[t][0..7], cw[t][8]=1.0 (shared expert).
// Also casts x row to bf16 (fused, x row already in registers).
// ---------------------------------------------------------------------------
__global__ __launch_bounds__(256) void k_gate(const float* __restrict__ x,
                                              const float* __restrict__ gw,
                                              __bf16* __restrict__ xb,
                                              float* __restrict__ cw) {
  const int wv = threadIdx.x >> 6, lane = threadIdx.x & 63;
  const int t = blockIdx.x * 4 + wv;
  const float* xr = x + (size_t)t * HDIM + lane * 16;
  float4 xv[4];
#pragma unroll
  for (int j = 0; j < 4; j++) xv[j] = ((const float4*)xr)[j];

  // bf16 cast-store: 16 elements = two bf16x8 stores (32B contiguous/lane)
  bf16x8 v0, v1;
#pragma unroll
  for (int j = 0; j < 8; j++) v0[j] = (__bf16)((const float*)xv)[j];
#pragma unroll
  for (int j = 0; j < 8; j++) v1[j] = (__bf16)((const float*)xv)[j + 8];
  bf16x8* xbo = (bf16x8*)(xb + (size_t)t * HDIM + lane * 16);
  xbo[0] = v0;
  xbo[1] = v1;

  float acc[8];
#pragma unroll
  for (int e = 0; e < 8; e++) {
    const float4* gp = (const float4*)(gw + e * HDIM + lane * 16);
    float s = 0.f;
#pragma unroll
    for (int j = 0; j < 4; j++) {
      float4 g = gp[j];
      s += xv[j].x * g.x + xv[j].y * g.y + xv[j].z * g.z + xv[j].w * g.w;
    }
    acc[e] = s;
  }
#pragma unroll
  for (int d = 32; d >= 1; d >>= 1) {
#pragma unroll
    for (int e = 0; e < 8; e++) acc[e] += __shfl_xor(acc[e], d, 64);
  }
  if (lane == 0) {
    float mx = acc[0];
#pragma unroll
    for (int e = 1; e < 8; e++) mx = fmaxf(mx, acc[e]);
    float p[8], Z = 0.f;
#pragma unroll
    for (int e = 0; e < 8; e++) {
      p[e] = expf(acc[e] - mx);
      Z += p[e];
    }
#pragma unroll
    for (int e = 0; e < 8; e++) p[e] /= Z;
    int i1 = 0;
#pragma unroll
    for (int e = 1; e < 8; e++)
      if (p[e] > p[i1]) i1 = e;  // first-max wins ties (matches jax top_k)
    int i2 = (i1 == 0) ? 1 : 0;
#pragma unroll
    for (int e = 0; e < 8; e++)
      if (e != i1 && p[e] > p[i2]) i2 = e;
    const float s12 = p[i1] + p[i2] + 1e-20f;
    float r[NE];
#pragma unroll
    for (int e = 0; e < NE; e++) r[e] = 0.f;
    r[i1] = p[i1] / s12;
    r[i2] = p[i2] / s12;
    r[8] = 1.0f;  // shared expert
#pragma unroll
    for (int e = 0; e < NE; e++) cw[t * NE + e] = r[e];
  }
}

// ---------------------------------------------------------------------------
// Transpose+cast: src fp32 [R][C] (batches 0..7 from w8, batch 8 from w1)
//                 -> out bf16 [b][C][R]
// ---------------------------------------------------------------------------
__global__ __launch_bounds__(256) void k_transpose(const float* __restrict__ w8,
                                                   const float* __restrict__ w1,
                                                   __bf16* __restrict__ out,
                                                   int R, int C) {
  __shared__ float tile[32][33];
  const int b = blockIdx.z;
  const float* src = (b < 8) ? (w8 + (size_t)b * R * C) : w1;
  const int c0 = blockIdx.x * 32, r0 = blockIdx.y * 32;
  const int tx = threadIdx.x & 31, ty = threadIdx.x >> 5;
#pragma unroll
  for (int i = 0; i < 4; i++)
    tile[ty + i * 8][tx] = src[(size_t)(r0 + ty + i * 8) * C + c0 + tx];
  __syncthreads();
#pragma unroll
  for (int i = 0; i < 4; i++)
    out[(size_t)b * R * C + (size_t)(c0 + ty + i * 8) * R + r0 + tx] =
        (__bf16)tile[tx][ty + i * 8];
}

// ---------------------------------------------------------------------------
// Phase A: per expert e, G = X@Wg[e], U = X@Wu[e],
//          inter[e] = cw[:,e] * gelu_exact(G) * U   (bf16)
// Block: 256 thr = 4 waves (2x2), tile 128(M=tokens) x 128(N=I cols), BK=32.
// ---------------------------------------------------------------------------
__global__ __launch_bounds__(256) void k_gu(const __bf16* __restrict__ xb,
                                            const __bf16* __restrict__ WgT,
                                            const __bf16* __restrict__ WuT,
                                            const float* __restrict__ cw,
                                            __bf16* __restrict__ inter) {
  __shared__ __bf16 sA[128][32];
  __shared__ __bf16 sG[128][32];
  __shared__ __bf16 sU[128][32];
  const int tid = threadIdx.x;
  const int w = tid >> 6, lane = tid & 63;
  const int m0 = blockIdx.x * 128, n0 = blockIdx.y * 128, e = blockIdx.z;

  const int off = tid * 16;  // staging byte offset, round 0
  const int r0 = off >> 6, cb = off & 63;
  const int r1 = r0 + 64;

  // row stride = 1024 bf16 = 2048 B (both X and W*T have H-contiguous rows)
  const char* gA0 = (const char*)xb + (size_t)(m0 + r0) * 2048 + cb;
  const char* gA1 = (const char*)xb + (size_t)(m0 + r1) * 2048 + cb;
  const char* wgb = (const char*)(WgT + (size_t)e * IDIM * HDIM);
  const char* wub = (const char*)(WuT + (size_t)e * IDIM * HDIM);
  const char* gG0 = wgb + (size_t)(n0 + r0) * 2048 + cb;
  const char* gG1 = wgb + (size_t)(n0 + r1) * 2048 + cb;
  const char* gU0 = wub + (size_t)(n0 + r0) * 2048 + cb;
  const char* gU1 = wub + (size_t)(n0 + r1) * 2048 + cb;

  char* sA0 = (char*)&sA[0][0] + w * 1024;
  char* sA1 = sA0 + 4096;
  char* sG0 = (char*)&sG[0][0] + w * 1024;
  char* sG1 = sG0 + 4096;
  char* sU0 = (char*)&sU[0][0] + w * 1024;
  char* sU1 = sU0 + 4096;

  const int quad = lane >> 4, l16 = lane & 15;
  const int wm = (w & 1) * 64, wn = (w >> 1) * 64;

  f32x4 zero4 = {0.f, 0.f, 0.f, 0.f};
  f32x4 accg[4][4], accu[4][4];
#pragma unroll
  for (int im = 0; im < 4; im++)
#pragma unroll
    for (int in = 0; in < 4; in++) {
      accg[im][in] = zero4;
      accu[im][in] = zero4;
    }

  for (int k = 0; k < HDIM; k += 32) {
    __syncthreads();
    load_lds16(gA0, sA0);
    load_lds16(gA1, sA1);
    load_lds16(gG0, sG0);
    load_lds16(gG1, sG1);
    load_lds16(gU0, sU0);
    load_lds16(gU1, sU1);
    gA0 += 64; gA1 += 64; gG0 += 64; gG1 += 64; gU0 += 64; gU1 += 64;
    __syncthreads();
    bf16x8 af[4], gf[4], uf[4];
#pragma unroll
    for (int i = 0; i < 4; i++) {
      af[i] = *(const bf16x8*)&sA[wm + i * 16 + l16][quad * 8];
      gf[i] = *(const bf16x8*)&sG[wn + i * 16 + l16][quad * 8];
      uf[i] = *(const bf16x8*)&sU[wn + i * 16 + l16][quad * 8];
    }
#pragma unroll
    for (int im = 0; im < 4; im++)
#pragma unroll
      for (int in = 0; in < 4; in++) {
        accg[im][in] = mfma_bf16(af[im], gf[in], accg[im][in]);
        accu[im][in] = mfma_bf16(af[im], uf[in], accu[im][in]);
      }
  }

  // epilogue: C/D layout col=lane&15, row=quad*4+r
#pragma unroll
  for (int im = 0; im < 4; im++) {
#pragma unroll
    for (int r = 0; r < 4; r++) {
      const int t = m0 + wm + im * 16 + quad * 4 + r;
      const float wt = cw[t * NE + e];
#pragma unroll
      for (int in = 0; in < 4; in++) {
        const int ic = n0 + wn + in * 16 + l16;
        const float g = accg[im][in][r];
        const float u = accu[im][in][r];
        const float v =
            wt * u * 0.5f * g * (1.0f + erff(g * 0.70710678118654752f));
        inter[((size_t)e * T_TOTAL + t) * IDIM + ic] = (__bf16)v;
      }
    }
  }
}

// ---------------------------------------------------------------------------
// Phase B: out[T][H] = sum_e inter[e] @ Wd[e]   (K = 9*512, fp32 out)
// ---------------------------------------------------------------------------
__global__ __launch_bounds__(256) void k_down(const __bf16* __restrict__ inter,
                                              const __bf16* __restrict__ WdT,
                                              float* __restrict__ out) {
  __shared__ __bf16 sA[128][32];
  __shared__ __bf16 sB[128][32];
  const int tid = threadIdx.x;
  const int w = tid >> 6, lane = tid & 63;
  const int m0 = blockIdx.x * 128, n0 = blockIdx.y * 128;

  const int off = tid * 16;
  const int r0 = off >> 6, cb = off & 63;
  const int r1 = r0 + 64;

  char* sA0 = (char*)&sA[0][0] + w * 1024;
  char* sA1 = sA0 + 4096;
  char* sB0 = (char*)&sB[0][0] + w * 1024;
  char* sB1 = sB0 + 4096;

  const int quad = lane >> 4, l16 = lane & 15;
  const int wm = (w & 1) * 64, wn = (w >> 1) * 64;

  f32x4 zero4 = {0.f, 0.f, 0.f, 0.f};
  f32x4 acc[4][4];
#pragma unroll
  for (int im = 0; im < 4; im++)
#pragma unroll
    for (int in = 0; in < 4; in++) acc[im][in] = zero4;

  for (int e = 0; e < NE; e++) {
    // inter rows: 512 bf16 = 1024 B; WdT rows: 512 bf16 = 1024 B
    const char* gA0 =
        (const char*)inter + ((size_t)e * T_TOTAL + m0 + r0) * 1024 + cb;
    const char* gA1 =
        (const char*)inter + ((size_t)e * T_TOTAL + m0 + r1) * 1024 + cb;
    const char* gB0 =
        (const char*)WdT + ((size_t)e * HDIM + n0 + r0) * 1024 + cb;
    const char* gB1 =
        (const char*)WdT + ((size_t)e * HDIM + n0 + r1) * 1024 + cb;
    for (int k = 0; k < IDIM; k += 32) {
      __syncthreads();
      load_lds16(gA0, sA0);
      load_lds16(gA1, sA1);
      load_lds16(gB0, sB0);
      load_lds16(gB1, sB1);
      gA0 += 64; gA1 += 64; gB0 += 64; gB1 += 64;
      __syncthreads();
      bf16x8 af[4], bfr[4];
#pragma unroll
      for (int i = 0; i < 4; i++) {
        af[i] = *(const bf16x8*)&sA[wm + i * 16 + l16][quad * 8];
        bfr[i] = *(const bf16x8*)&sB[wn + i * 16 + l16][quad * 8];
      }
#pragma unroll
      for (int im = 0; im < 4; im++)
#pragma unroll
        for (int in = 0; in < 4; in++)
          acc[im][in] = mfma_bf16(af[im], bfr[in], acc[im][in]);
    }
  }

#pragma unroll
  for (int im = 0; im < 4; im++) {
#pragma unroll
    for (int r = 0; r < 4; r++) {
      const int t = m0 + wm + im * 16 + quad * 4 + r;
#pragma unroll
      for (int in = 0; in < 4; in++) {
        out[(size_t)t * HDIM + n0 + wn + in * 16 + l16] = acc[im][in][r];
      }
    }
  }
}

// ---------------------------------------------------------------------------
extern "C" void kernel_launch(void* const* d_in, const int* in_sizes, int n_in,
                              void* d_out, int out_size, void* d_ws,
                              size_t ws_size, hipStream_t stream) {
  const float* x = (const float*)d_in[0];
  const float* gw = (const float*)d_in[1];
  const float* Wg = (const float*)d_in[2];
  const float* Wu = (const float*)d_in[3];
  const float* Wd = (const float*)d_in[4];
  const float* sWg = (const float*)d_in[5];
  const float* sWu = (const float*)d_in[6];
  const float* sWd = (const float*)d_in[7];
  float* out = (float*)d_out;

  char* ws = (char*)d_ws;
  size_t off = 0;
  auto alloc = [&](size_t n) {
    char* p = ws + off;
    off += (n + 255) & ~(size_t)255;
    return p;
  };
  __bf16* xb = (__bf16*)alloc((size_t)T_TOTAL * HDIM * 2);          // 33.5 MB
  __bf16* WgT = (__bf16*)alloc((size_t)NE * IDIM * HDIM * 2);       // 9.4 MB
  __bf16* WuT = (__bf16*)alloc((size_t)NE * IDIM * HDIM * 2);       // 9.4 MB
  __bf16* WdT = (__bf16*)alloc((size_t)NE * HDIM * IDIM * 2);       // 9.4 MB
  float* cw = (float*)alloc((size_t)T_TOTAL * NE * 4);              // 0.6 MB
  __bf16* inter = (__bf16*)alloc((size_t)NE * T_TOTAL * IDIM * 2);  // 151 MB

  k_gate<<<dim3(T_TOTAL / 4), dim3(256), 0, stream>>>(x, gw, xb, cw);
  // Wg [8][H][I] + sWg [H][I] -> WgT [9][I][H]
  k_transpose<<<dim3(IDIM / 32, HDIM / 32, NE), dim3(256), 0, stream>>>(
      Wg, sWg, WgT, HDIM, IDIM);
  k_transpose<<<dim3(IDIM / 32, HDIM / 32, NE), dim3(256), 0, stream>>>(
      Wu, sWu, WuT, HDIM, IDIM);
  // Wd [8][I][H] + sWd [I][H] -> WdT [9][H][I]
  k_transpose<<<dim3(HDIM / 32, IDIM / 32, NE), dim3(256), 0, stream>>>(
      Wd, sWd, WdT, IDIM, HDIM);

  k_gu<<<dim3(T_TOTAL / 128, IDIM / 128, NE), dim3(256), 0, stream>>>(
      xb, WgT, WuT, cw, inter);
  k_down<<<dim3(T_TOTAL / 128, HDIM / 128), dim3(256), 0, stream>>>(inter, WdT,
                                                                    out);
}

// Round 2
// 1062.803 us; speedup vs baseline: 1.0631x; 1.0631x over previous
//
#include <hip/hip_runtime.h>
#include <hip/hip_bf16.h>
#include <math.h>

// ---------------------------------------------------------------------------
// DeepseekV2 MoE: T=16384 tokens, H=1024, E=8 routed (top-2) + 1 shared, I=512
// Round 2: token-gather sparsity. Gate builds per-expert slot lists; phase A
// (gate/up+gelu) runs only over routed slots (2T) + shared (T); phase B
// down-proj: shared expert plain-stores out, routed experts atomic-add.
// bf16 MFMA 16x16x32, m97-style 128x128 tiles, global_load_lds width-16.
// ---------------------------------------------------------------------------

#define T_TOTAL 16384
#define HDIM 1024
#define IDIM 512
#define NE 9  // 8 routed + 1 shared (expert index 8)

typedef __bf16 bf16x8 __attribute__((ext_vector_type(8)));
typedef float f32x4 __attribute__((ext_vector_type(4)));

typedef __attribute__((address_space(1))) void gvoid_t;
typedef __attribute__((address_space(3))) void lvoid_t;

__device__ __forceinline__ void load_lds16(const void* g, void* l) {
  // 16B per lane; LDS dest = wave-uniform base + lane*16 (src may scatter)
  __builtin_amdgcn_global_load_lds((const gvoid_t*)g, (lvoid_t*)l, 16, 0, 0);
}

__device__ __forceinline__ f32x4 mfma_bf16(bf16x8 a, bf16x8 b, f32x4 c) {
  return __builtin_amdgcn_mfma_f32_16x16x32_bf16(a, b, c, 0, 0, 0);
}

// ---------------------------------------------------------------------------
// Gate: one wave per token. fp32 logits -> softmax -> top2 -> normalized
// weights; assigns (token, weight) to per-expert slot lists via atomics.
// Also casts x row to bf16.
// ---------------------------------------------------------------------------
__global__ __launch_bounds__(256) void k_gate(const float* __restrict__ x,
                                              const float* __restrict__ gw,
                                              __bf16* __restrict__ xb,
                                              int* __restrict__ tok,
                                              float* __restrict__ wtl,
                                              int* __restrict__ cnt) {
  const int wv = threadIdx.x >> 6, lane = threadIdx.x & 63;
  const int t = blockIdx.x * 4 + wv;
  const float* xr = x + (size_t)t * HDIM + lane * 16;
  float4 xv[4];
#pragma unroll
  for (int j = 0; j < 4; j++) xv[j] = ((const float4*)xr)[j];

  bf16x8 v0, v1;
#pragma unroll
  for (int j = 0; j < 8; j++) v0[j] = (__bf16)((const float*)xv)[j];
#pragma unroll
  for (int j = 0; j < 8; j++) v1[j] = (__bf16)((const float*)xv)[j + 8];
  bf16x8* xbo = (bf16x8*)(xb + (size_t)t * HDIM + lane * 16);
  xbo[0] = v0;
  xbo[1] = v1;

  float acc[8];
#pragma unroll
  for (int e = 0; e < 8; e++) {
    const float4* gp = (const float4*)(gw + e * HDIM + lane * 16);
    float s = 0.f;
#pragma unroll
    for (int j = 0; j < 4; j++) {
      float4 g = gp[j];
      s += xv[j].x * g.x + xv[j].y * g.y + xv[j].z * g.z + xv[j].w * g.w;
    }
    acc[e] = s;
  }
#pragma unroll
  for (int d = 32; d >= 1; d >>= 1) {
#pragma unroll
    for (int e = 0; e < 8; e++) acc[e] += __shfl_xor(acc[e], d, 64);
  }
  if (lane == 0) {
    float mx = acc[0];
#pragma unroll
    for (int e = 1; e < 8; e++) mx = fmaxf(mx, acc[e]);
    float p[8], Z = 0.f;
#pragma unroll
    for (int e = 0; e < 8; e++) {
      p[e] = expf(acc[e] - mx);
      Z += p[e];
    }
#pragma unroll
    for (int e = 0; e < 8; e++) p[e] /= Z;
    int i1 = 0;
#pragma unroll
    for (int e = 1; e < 8; e++)
      if (p[e] > p[i1]) i1 = e;  // first-max wins ties (matches jax top_k)
    int i2 = (i1 == 0) ? 1 : 0;
#pragma unroll
    for (int e = 0; e < 8; e++)
      if (e != i1 && p[e] > p[i2]) i2 = e;
    const float s12 = p[i1] + p[i2] + 1e-20f;
    const int p1 = atomicAdd(&cnt[i1], 1);
    tok[i1 * T_TOTAL + p1] = t;
    wtl[i1 * T_TOTAL + p1] = p[i1] / s12;
    const int p2 = atomicAdd(&cnt[i2], 1);
    tok[i2 * T_TOTAL + p2] = t;
    wtl[i2 * T_TOTAL + p2] = p[i2] / s12;
  }
}

// ---------------------------------------------------------------------------
// Transpose+cast: src fp32 [R][C] (batches 0..7 from w8, batch 8 from w1)
//                 -> out bf16 [b][C][R]
// ---------------------------------------------------------------------------
__global__ __launch_bounds__(256) void k_transpose(const float* __restrict__ w8,
                                                   const float* __restrict__ w1,
                                                   __bf16* __restrict__ out,
                                                   int R, int C) {
  __shared__ float tile[32][33];
  const int b = blockIdx.z;
  const float* src = (b < 8) ? (w8 + (size_t)b * R * C) : w1;
  const int c0 = blockIdx.x * 32, r0 = blockIdx.y * 32;
  const int tx = threadIdx.x & 31, ty = threadIdx.x >> 5;
#pragma unroll
  for (int i = 0; i < 4; i++)
    tile[ty + i * 8][tx] = src[(size_t)(r0 + ty + i * 8) * C + c0 + tx];
  __syncthreads();
#pragma unroll
  for (int i = 0; i < 4; i++)
    out[(size_t)b * R * C + (size_t)(c0 + ty + i * 8) * R + r0 + tx] =
        (__bf16)tile[tx][ty + i * 8];
}

// ---------------------------------------------------------------------------
// Phase A (sparse): for expert e, over its slot list: G = X_g @ Wg[e],
// U = X_g @ Wu[e]; inter[e][slot] = wt * gelu_exact(G) * U  (bf16)
// Block: 256 thr = 4 waves (2x2), tile 128(slots) x 128(I-cols), BK=32.
// e == 8 is the shared expert: identity slot list, wt = 1, all T tokens.
// ---------------------------------------------------------------------------
__global__ __launch_bounds__(256) void k_gu(const __bf16* __restrict__ xb,
                                            const __bf16* __restrict__ WgT,
                                            const __bf16* __restrict__ WuT,
                                            const int* __restrict__ tok,
                                            const float* __restrict__ wtl,
                                            const int* __restrict__ cnt,
                                            __bf16* __restrict__ inter) {
  const int e = blockIdx.z;
  const bool se = (e == 8);
  const int cnt_e = se ? T_TOTAL : cnt[e];
  const int m0 = blockIdx.x * 128;
  if (m0 >= cnt_e) return;  // uniform early-exit, before any barrier

  __shared__ __bf16 sA[128][32];
  __shared__ __bf16 sG[128][32];
  __shared__ __bf16 sU[128][32];
  const int tid = threadIdx.x;
  const int w = tid >> 6, lane = tid & 63;
  const int n0 = blockIdx.y * 128;

  const int off = tid * 16;
  const int r0 = off >> 6, cb = off & 63;
  const int r1 = r0 + 64;

  // gathered A rows (clamped for partial tail blocks; stores are masked)
  int s0 = m0 + r0; if (s0 > cnt_e - 1) s0 = cnt_e - 1;
  int s1 = m0 + r1; if (s1 > cnt_e - 1) s1 = cnt_e - 1;
  const int t0 = se ? s0 : tok[e * T_TOTAL + s0];
  const int t1 = se ? s1 : tok[e * T_TOTAL + s1];

  const char* gA0 = (const char*)xb + (size_t)t0 * 2048 + cb;
  const char* gA1 = (const char*)xb + (size_t)t1 * 2048 + cb;
  const char* wgb = (const char*)(WgT + (size_t)e * IDIM * HDIM);
  const char* wub = (const char*)(WuT + (size_t)e * IDIM * HDIM);
  const char* gG0 = wgb + (size_t)(n0 + r0) * 2048 + cb;
  const char* gG1 = wgb + (size_t)(n0 + r1) * 2048 + cb;
  const char* gU0 = wub + (size_t)(n0 + r0) * 2048 + cb;
  const char* gU1 = wub + (size_t)(n0 + r1) * 2048 + cb;

  char* sA0 = (char*)&sA[0][0] + w * 1024;
  char* sA1 = sA0 + 4096;
  char* sG0 = (char*)&sG[0][0] + w * 1024;
  char* sG1 = sG0 + 4096;
  char* sU0 = (char*)&sU[0][0] + w * 1024;
  char* sU1 = sU0 + 4096;

  const int quad = lane >> 4, l16 = lane & 15;
  const int wm = (w & 1) * 64, wn = (w >> 1) * 64;

  f32x4 zero4 = {0.f, 0.f, 0.f, 0.f};
  f32x4 accg[4][4], accu[4][4];
#pragma unroll
  for (int im = 0; im < 4; im++)
#pragma unroll
    for (int in = 0; in < 4; in++) {
      accg[im][in] = zero4;
      accu[im][in] = zero4;
    }

  for (int k = 0; k < HDIM; k += 32) {
    __syncthreads();
    load_lds16(gA0, sA0);
    load_lds16(gA1, sA1);
    load_lds16(gG0, sG0);
    load_lds16(gG1, sG1);
    load_lds16(gU0, sU0);
    load_lds16(gU1, sU1);
    gA0 += 64; gA1 += 64; gG0 += 64; gG1 += 64; gU0 += 64; gU1 += 64;
    __syncthreads();
    bf16x8 af[4], gf[4], uf[4];
#pragma unroll
    for (int i = 0; i < 4; i++) {
      af[i] = *(const bf16x8*)&sA[wm + i * 16 + l16][quad * 8];
      gf[i] = *(const bf16x8*)&sG[wn + i * 16 + l16][quad * 8];
      uf[i] = *(const bf16x8*)&sU[wn + i * 16 + l16][quad * 8];
    }
#pragma unroll
    for (int im = 0; im < 4; im++)
#pragma unroll
      for (int in = 0; in < 4; in++) {
        accg[im][in] = mfma_bf16(af[im], gf[in], accg[im][in]);
        accu[im][in] = mfma_bf16(af[im], uf[in], accu[im][in]);
      }
  }

  // epilogue: C/D layout col=lane&15, row=quad*4+r; store only valid slots
#pragma unroll
  for (int im = 0; im < 4; im++) {
#pragma unroll
    for (int r = 0; r < 4; r++) {
      const int slot = m0 + wm + im * 16 + quad * 4 + r;
      if (slot < cnt_e) {
        const float wt = se ? 1.0f : wtl[e * T_TOTAL + slot];
#pragma unroll
        for (int in = 0; in < 4; in++) {
          const int ic = n0 + wn + in * 16 + l16;
          const float g = accg[im][in][r];
          const float u = accu[im][in][r];
          const float v =
              wt * u * 0.5f * g * (1.0f + erff(g * 0.70710678118654752f));
          inter[((size_t)e * T_TOTAL + slot) * IDIM + ic] = (__bf16)v;
        }
      }
    }
  }
}

// ---------------------------------------------------------------------------
// Phase B shared: out[T][H] = inter[8] @ Wd[8]  (plain stores, runs first)
// ---------------------------------------------------------------------------
__global__ __launch_bounds__(256) void k_down_s(const __bf16* __restrict__ iA,
                                                const __bf16* __restrict__ wB,
                                                float* __restrict__ out) {
  __shared__ __bf16 sA[128][32];
  __shared__ __bf16 sB[128][32];
  const int tid = threadIdx.x;
  const int w = tid >> 6, lane = tid & 63;
  const int m0 = blockIdx.x * 128, n0 = blockIdx.y * 128;

  const int off = tid * 16;
  const int r0 = off >> 6, cb = off & 63;
  const int r1 = r0 + 64;

  const char* gA0 = (const char*)iA + (size_t)(m0 + r0) * 1024 + cb;
  const char* gA1 = (const char*)iA + (size_t)(m0 + r1) * 1024 + cb;
  const char* gB0 = (const char*)wB + (size_t)(n0 + r0) * 1024 + cb;
  const char* gB1 = (const char*)wB + (size_t)(n0 + r1) * 1024 + cb;

  char* sA0 = (char*)&sA[0][0] + w * 1024;
  char* sA1 = sA0 + 4096;
  char* sB0 = (char*)&sB[0][0] + w * 1024;
  char* sB1 = sB0 + 4096;

  const int quad = lane >> 4, l16 = lane & 15;
  const int wm = (w & 1) * 64, wn = (w >> 1) * 64;

  f32x4 zero4 = {0.f, 0.f, 0.f, 0.f};
  f32x4 acc[4][4];
#pragma unroll
  for (int im = 0; im < 4; im++)
#pragma unroll
    for (int in = 0; in < 4; in++) acc[im][in] = zero4;

  for (int k = 0; k < IDIM; k += 32) {
    __syncthreads();
    load_lds16(gA0, sA0);
    load_lds16(gA1, sA1);
    load_lds16(gB0, sB0);
    load_lds16(gB1, sB1);
    gA0 += 64; gA1 += 64; gB0 += 64; gB1 += 64;
    __syncthreads();
    bf16x8 af[4], bfr[4];
#pragma unroll
    for (int i = 0; i < 4; i++) {
      af[i] = *(const bf16x8*)&sA[wm + i * 16 + l16][quad * 8];
      bfr[i] = *(const bf16x8*)&sB[wn + i * 16 + l16][quad * 8];
    }
#pragma unroll
    for (int im = 0; im < 4; im++)
#pragma unroll
      for (int in = 0; in < 4; in++)
        acc[im][in] = mfma_bf16(af[im], bfr[in], acc[im][in]);
  }

#pragma unroll
  for (int im = 0; im < 4; im++) {
#pragma unroll
    for (int r = 0; r < 4; r++) {
      const int t = m0 + wm + im * 16 + quad * 4 + r;
#pragma unroll
      for (int in = 0; in < 4; in++)
        out[(size_t)t * HDIM + n0 + wn + in * 16 + l16] = acc[im][in][r];
    }
  }
}

// ---------------------------------------------------------------------------
// Phase B routed: per expert e, gathered GEMM inter[e][0..cnt) @ Wd[e],
// scatter atomic-add into out rows (runs after k_down_s initialized out).
// ---------------------------------------------------------------------------
__global__ __launch_bounds__(256) void k_down_r(const __bf16* __restrict__ inter,
                                                const __bf16* __restrict__ WdT,
                                                const int* __restrict__ tok,
                                                const int* __restrict__ cnt,
                                                float* __restrict__ out) {
  const int e = blockIdx.z;
  const int cnt_e = cnt[e];
  const int m0 = blockIdx.x * 128;
  if (m0 >= cnt_e) return;

  __shared__ __bf16 sA[128][32];
  __shared__ __bf16 sB[128][32];
  const int tid = threadIdx.x;
  const int w = tid >> 6, lane = tid & 63;
  const int n0 = blockIdx.y * 128;

  const int off = tid * 16;
  const int r0 = off >> 6, cb = off & 63;
  const int r1 = r0 + 64;

  int s0 = m0 + r0; if (s0 > cnt_e - 1) s0 = cnt_e - 1;
  int s1 = m0 + r1; if (s1 > cnt_e - 1) s1 = cnt_e - 1;

  const char* gA0 =
      (const char*)inter + ((size_t)e * T_TOTAL + s0) * 1024 + cb;
  const char* gA1 =
      (const char*)inter + ((size_t)e * T_TOTAL + s1) * 1024 + cb;
  const char* gB0 = (const char*)WdT + ((size_t)e * HDIM + n0 + r0) * 1024 + cb;
  const char* gB1 = (const char*)WdT + ((size_t)e * HDIM + n0 + r1) * 1024 + cb;

  char* sA0 = (char*)&sA[0][0] + w * 1024;
  char* sA1 = sA0 + 4096;
  char* sB0 = (char*)&sB[0][0] + w * 1024;
  char* sB1 = sB0 + 4096;

  const int quad = lane >> 4, l16 = lane & 15;
  const int wm = (w & 1) * 64, wn = (w >> 1) * 64;

  f32x4 zero4 = {0.f, 0.f, 0.f, 0.f};
  f32x4 acc[4][4];
#pragma unroll
  for (int im = 0; im < 4; im++)
#pragma unroll
    for (int in = 0; in < 4; in++) acc[im][in] = zero4;

  for (int k = 0; k < IDIM; k += 32) {
    __syncthreads();
    load_lds16(gA0, sA0);
    load_lds16(gA1, sA1);
    load_lds16(gB0, sB0);
    load_lds16(gB1, sB1);
    gA0 += 64; gA1 += 64; gB0 += 64; gB1 += 64;
    __syncthreads();
    bf16x8 af[4], bfr[4];
#pragma unroll
    for (int i = 0; i < 4; i++) {
      af[i] = *(const bf16x8*)&sA[wm + i * 16 + l16][quad * 8];
      bfr[i] = *(const bf16x8*)&sB[wn + i * 16 + l16][quad * 8];
    }
#pragma unroll
    for (int im = 0; im < 4; im++)
#pragma unroll
      for (int in = 0; in < 4; in++)
        acc[im][in] = mfma_bf16(af[im], bfr[in], acc[im][in]);
  }

#pragma unroll
  for (int im = 0; im < 4; im++) {
#pragma unroll
    for (int r = 0; r < 4; r++) {
      const int slot = m0 + wm + im * 16 + quad * 4 + r;
      if (slot < cnt_e) {
        const int t = tok[e * T_TOTAL + slot];
#pragma unroll
        for (int in = 0; in < 4; in++)
          atomicAdd(&out[(size_t)t * HDIM + n0 + wn + in * 16 + l16],
                    acc[im][in][r]);
      }
    }
  }
}

// ---------------------------------------------------------------------------
extern "C" void kernel_launch(void* const* d_in, const int* in_sizes, int n_in,
                              void* d_out, int out_size, void* d_ws,
                              size_t ws_size, hipStream_t stream) {
  const float* x = (const float*)d_in[0];
  const float* gw = (const float*)d_in[1];
  const float* Wg = (const float*)d_in[2];
  const float* Wu = (const float*)d_in[3];
  const float* Wd = (const float*)d_in[4];
  const float* sWg = (const float*)d_in[5];
  const float* sWu = (const float*)d_in[6];
  const float* sWd = (const float*)d_in[7];
  float* out = (float*)d_out;

  char* ws = (char*)d_ws;
  size_t off = 0;
  auto alloc = [&](size_t n) {
    char* p = ws + off;
    off += (n + 255) & ~(size_t)255;
    return p;
  };
  __bf16* xb = (__bf16*)alloc((size_t)T_TOTAL * HDIM * 2);          // 33.5 MB
  __bf16* WgT = (__bf16*)alloc((size_t)NE * IDIM * HDIM * 2);       // 9.4 MB
  __bf16* WuT = (__bf16*)alloc((size_t)NE * IDIM * HDIM * 2);       // 9.4 MB
  __bf16* WdT = (__bf16*)alloc((size_t)NE * HDIM * IDIM * 2);       // 9.4 MB
  int* tok = (int*)alloc((size_t)8 * T_TOTAL * 4);                  // 512 KB
  float* wtl = (float*)alloc((size_t)8 * T_TOTAL * 4);              // 512 KB
  int* cnt = (int*)alloc(8 * 4);
  __bf16* inter = (__bf16*)alloc((size_t)NE * T_TOTAL * IDIM * 2);  // 151 MB

  hipMemsetAsync(cnt, 0, 8 * 4, stream);

  k_gate<<<dim3(T_TOTAL / 4), dim3(256), 0, stream>>>(x, gw, xb, tok, wtl, cnt);
  // Wg [8][H][I] + sWg [H][I] -> WgT [9][I][H]
  k_transpose<<<dim3(IDIM / 32, HDIM / 32, NE), dim3(256), 0, stream>>>(
      Wg, sWg, WgT, HDIM, IDIM);
  k_transpose<<<dim3(IDIM / 32, HDIM / 32, NE), dim3(256), 0, stream>>>(
      Wu, sWu, WuT, HDIM, IDIM);
  // Wd [8][I][H] + sWd [I][H] -> WdT [9][H][I]
  k_transpose<<<dim3(HDIM / 32, IDIM / 32, NE), dim3(256), 0, stream>>>(
      Wd, sWd, WdT, IDIM, HDIM);

  // Phase A: grid covers worst case (any expert up to T tokens); early-exit.
  k_gu<<<dim3(T_TOTAL / 128, IDIM / 128, NE), dim3(256), 0, stream>>>(
      xb, WgT, WuT, tok, wtl, cnt, inter);

  // Phase B: shared expert first (plain stores initialize out) ...
  k_down_s<<<dim3(T_TOTAL / 128, HDIM / 128), dim3(256), 0, stream>>>(
      inter + (size_t)8 * T_TOTAL * IDIM, WdT + (size_t)8 * HDIM * IDIM, out);
  // ... then routed experts atomic-add on top.
  k_down_r<<<dim3(T_TOTAL / 128, HDIM / 128, 8), dim3(256), 0, stream>>>(
      inter, WdT, tok, cnt, out);
}

// Round 3
// 723.038 us; speedup vs baseline: 1.5626x; 1.4699x over previous
//
#include <hip/hip_runtime.h>
#include <hip/hip_bf16.h>
#include <math.h>

// ---------------------------------------------------------------------------
// DeepseekV2 MoE: T=16384 tokens, H=1024, E=8 routed (top-2) + 1 shared, I=512
// Round 3: fix k_gate atomic contention (394 us -> ~50 us predicted).
// Block-aggregated slot assignment: LDS histogram + 8 global atomics/block
// (2048 total vs 32768 round-2), counters padded to 64B stride.
// Phases A/B unchanged from round 2 (sparse gather + atomic scatter-add).
// ---------------------------------------------------------------------------

#define T_TOTAL 16384
#define HDIM 1024
#define IDIM 512
#define NE 9  // 8 routed + 1 shared (expert index 8)
#define CNT_STRIDE 16  // pad cnt[] entries to 64B so L2 slices work in parallel

typedef __bf16 bf16x8 __attribute__((ext_vector_type(8)));
typedef float f32x4 __attribute__((ext_vector_type(4)));

typedef __attribute__((address_space(1))) void gvoid_t;
typedef __attribute__((address_space(3))) void lvoid_t;

__device__ __forceinline__ void load_lds16(const void* g, void* l) {
  // 16B per lane; LDS dest = wave-uniform base + lane*16 (src may scatter)
  __builtin_amdgcn_global_load_lds((const gvoid_t*)g, (lvoid_t*)l, 16, 0, 0);
}

__device__ __forceinline__ f32x4 mfma_bf16(bf16x8 a, bf16x8 b, f32x4 c) {
  return __builtin_amdgcn_mfma_f32_16x16x32_bf16(a, b, c, 0, 0, 0);
}

// ---------------------------------------------------------------------------
// Gate: 256 blocks x 64 tokens (4 waves x 16 tokens). Per token: fp32 logits,
// softmax, top-2, normalized weights. Slot assignment block-aggregated:
// LDS histogram -> local rank, 8 global atomics/block reserve base ranges.
// Also casts x rows to bf16.
// ---------------------------------------------------------------------------
__global__ __launch_bounds__(256) void k_gate(const float* __restrict__ x,
                                              const float* __restrict__ gw,
                                              __bf16* __restrict__ xb,
                                              int* __restrict__ tok,
                                              float* __restrict__ wtl,
                                              int* __restrict__ cnt) {
  __shared__ int s_eid[64][2];
  __shared__ float s_wt[64][2];
  __shared__ int s_rank[64][2];
  __shared__ int lcnt[8];
  __shared__ int lbase[8];
  const int wv = threadIdx.x >> 6, lane = threadIdx.x & 63;
  if (threadIdx.x < 8) lcnt[threadIdx.x] = 0;
  __syncthreads();

  for (int i = 0; i < 16; i++) {
    const int tl = wv * 16 + i;
    const int t = blockIdx.x * 64 + tl;
    const float* xr = x + (size_t)t * HDIM + lane * 16;
    float4 xv[4];
#pragma unroll
    for (int j = 0; j < 4; j++) xv[j] = ((const float4*)xr)[j];

    bf16x8 v0, v1;
#pragma unroll
    for (int j = 0; j < 8; j++) v0[j] = (__bf16)((const float*)xv)[j];
#pragma unroll
    for (int j = 0; j < 8; j++) v1[j] = (__bf16)((const float*)xv)[j + 8];
    bf16x8* xbo = (bf16x8*)(xb + (size_t)t * HDIM + lane * 16);
    xbo[0] = v0;
    xbo[1] = v1;

    float acc[8];
#pragma unroll
    for (int e = 0; e < 8; e++) {
      const float4* gp = (const float4*)(gw + e * HDIM + lane * 16);
      float s = 0.f;
#pragma unroll
      for (int j = 0; j < 4; j++) {
        float4 g = gp[j];
        s += xv[j].x * g.x + xv[j].y * g.y + xv[j].z * g.z + xv[j].w * g.w;
      }
      acc[e] = s;
    }
#pragma unroll
    for (int d = 32; d >= 1; d >>= 1) {
#pragma unroll
      for (int e = 0; e < 8; e++) acc[e] += __shfl_xor(acc[e], d, 64);
    }
    if (lane == 0) {
      float mx = acc[0];
#pragma unroll
      for (int e = 1; e < 8; e++) mx = fmaxf(mx, acc[e]);
      float p[8], Z = 0.f;
#pragma unroll
      for (int e = 0; e < 8; e++) {
        p[e] = expf(acc[e] - mx);
        Z += p[e];
      }
#pragma unroll
      for (int e = 0; e < 8; e++) p[e] /= Z;
      int i1 = 0;
#pragma unroll
      for (int e = 1; e < 8; e++)
        if (p[e] > p[i1]) i1 = e;  // first-max wins ties (matches jax top_k)
      int i2 = (i1 == 0) ? 1 : 0;
#pragma unroll
      for (int e = 0; e < 8; e++)
        if (e != i1 && p[e] > p[i2]) i2 = e;
      const float s12 = p[i1] + p[i2] + 1e-20f;
      s_eid[tl][0] = i1;
      s_eid[tl][1] = i2;
      s_wt[tl][0] = p[i1] / s12;
      s_wt[tl][1] = p[i2] / s12;
    }
  }
  __syncthreads();

  // block-local histogram -> local ranks (LDS atomics, ~16 per counter)
  if (threadIdx.x < 64) {
    s_rank[threadIdx.x][0] = atomicAdd(&lcnt[s_eid[threadIdx.x][0]], 1);
    s_rank[threadIdx.x][1] = atomicAdd(&lcnt[s_eid[threadIdx.x][1]], 1);
  }
  __syncthreads();
  // one global reservation per expert per block (256 contenders/address)
  if (threadIdx.x < 8)
    lbase[threadIdx.x] =
        atomicAdd(&cnt[threadIdx.x * CNT_STRIDE], lcnt[threadIdx.x]);
  __syncthreads();
  if (threadIdx.x < 64) {
    const int t = blockIdx.x * 64 + threadIdx.x;
#pragma unroll
    for (int j = 0; j < 2; j++) {
      const int e = s_eid[threadIdx.x][j];
      const int slot = lbase[e] + s_rank[threadIdx.x][j];
      tok[e * T_TOTAL + slot] = t;
      wtl[e * T_TOTAL + slot] = s_wt[threadIdx.x][j];
    }
  }
}

// ---------------------------------------------------------------------------
// Transpose+cast: src fp32 [R][C] (batches 0..7 from w8, batch 8 from w1)
//                 -> out bf16 [b][C][R]
// ---------------------------------------------------------------------------
__global__ __launch_bounds__(256) void k_transpose(const float* __restrict__ w8,
                                                   const float* __restrict__ w1,
                                                   __bf16* __restrict__ out,
                                                   int R, int C) {
  __shared__ float tile[32][33];
  const int b = blockIdx.z;
  const float* src = (b < 8) ? (w8 + (size_t)b * R * C) : w1;
  const int c0 = blockIdx.x * 32, r0 = blockIdx.y * 32;
  const int tx = threadIdx.x & 31, ty = threadIdx.x >> 5;
#pragma unroll
  for (int i = 0; i < 4; i++)
    tile[ty + i * 8][tx] = src[(size_t)(r0 + ty + i * 8) * C + c0 + tx];
  __syncthreads();
#pragma unroll
  for (int i = 0; i < 4; i++)
    out[(size_t)b * R * C + (size_t)(c0 + ty + i * 8) * R + r0 + tx] =
        (__bf16)tile[tx][ty + i * 8];
}

// ---------------------------------------------------------------------------
// Phase A (sparse): for expert e, over its slot list: G = X_g @ Wg[e],
// U = X_g @ Wu[e]; inter[e][slot] = wt * gelu_exact(G) * U  (bf16)
// Block: 256 thr = 4 waves (2x2), tile 128(slots) x 128(I-cols), BK=32.
// e == 8 is the shared expert: identity slot list, wt = 1, all T tokens.
// ---------------------------------------------------------------------------
__global__ __launch_bounds__(256) void k_gu(const __bf16* __restrict__ xb,
                                            const __bf16* __restrict__ WgT,
                                            const __bf16* __restrict__ WuT,
                                            const int* __restrict__ tok,
                                            const float* __restrict__ wtl,
                                            const int* __restrict__ cnt,
                                            __bf16* __restrict__ inter) {
  const int e = blockIdx.z;
  const bool se = (e == 8);
  const int cnt_e = se ? T_TOTAL : cnt[e * CNT_STRIDE];
  const int m0 = blockIdx.x * 128;
  if (m0 >= cnt_e) return;  // uniform early-exit, before any barrier

  __shared__ __bf16 sA[128][32];
  __shared__ __bf16 sG[128][32];
  __shared__ __bf16 sU[128][32];
  const int tid = threadIdx.x;
  const int w = tid >> 6, lane = tid & 63;
  const int n0 = blockIdx.y * 128;

  const int off = tid * 16;
  const int r0 = off >> 6, cb = off & 63;
  const int r1 = r0 + 64;

  // gathered A rows (clamped for partial tail blocks; stores are masked)
  int s0 = m0 + r0; if (s0 > cnt_e - 1) s0 = cnt_e - 1;
  int s1 = m0 + r1; if (s1 > cnt_e - 1) s1 = cnt_e - 1;
  const int t0 = se ? s0 : tok[e * T_TOTAL + s0];
  const int t1 = se ? s1 : tok[e * T_TOTAL + s1];

  const char* gA0 = (const char*)xb + (size_t)t0 * 2048 + cb;
  const char* gA1 = (const char*)xb + (size_t)t1 * 2048 + cb;
  const char* wgb = (const char*)(WgT + (size_t)e * IDIM * HDIM);
  const char* wub = (const char*)(WuT + (size_t)e * IDIM * HDIM);
  const char* gG0 = wgb + (size_t)(n0 + r0) * 2048 + cb;
  const char* gG1 = wgb + (size_t)(n0 + r1) * 2048 + cb;
  const char* gU0 = wub + (size_t)(n0 + r0) * 2048 + cb;
  const char* gU1 = wub + (size_t)(n0 + r1) * 2048 + cb;

  char* sA0 = (char*)&sA[0][0] + w * 1024;
  char* sA1 = sA0 + 4096;
  char* sG0 = (char*)&sG[0][0] + w * 1024;
  char* sG1 = sG0 + 4096;
  char* sU0 = (char*)&sU[0][0] + w * 1024;
  char* sU1 = sU0 + 4096;

  const int quad = lane >> 4, l16 = lane & 15;
  const int wm = (w & 1) * 64, wn = (w >> 1) * 64;

  f32x4 zero4 = {0.f, 0.f, 0.f, 0.f};
  f32x4 accg[4][4], accu[4][4];
#pragma unroll
  for (int im = 0; im < 4; im++)
#pragma unroll
    for (int in = 0; in < 4; in++) {
      accg[im][in] = zero4;
      accu[im][in] = zero4;
    }

  for (int k = 0; k < HDIM; k += 32) {
    __syncthreads();
    load_lds16(gA0, sA0);
    load_lds16(gA1, sA1);
    load_lds16(gG0, sG0);
    load_lds16(gG1, sG1);
    load_lds16(gU0, sU0);
    load_lds16(gU1, sU1);
    gA0 += 64; gA1 += 64; gG0 += 64; gG1 += 64; gU0 += 64; gU1 += 64;
    __syncthreads();
    bf16x8 af[4], gf[4], uf[4];
#pragma unroll
    for (int i = 0; i < 4; i++) {
      af[i] = *(const bf16x8*)&sA[wm + i * 16 + l16][quad * 8];
      gf[i] = *(const bf16x8*)&sG[wn + i * 16 + l16][quad * 8];
      uf[i] = *(const bf16x8*)&sU[wn + i * 16 + l16][quad * 8];
    }
#pragma unroll
    for (int im = 0; im < 4; im++)
#pragma unroll
      for (int in = 0; in < 4; in++) {
        accg[im][in] = mfma_bf16(af[im], gf[in], accg[im][in]);
        accu[im][in] = mfma_bf16(af[im], uf[in], accu[im][in]);
      }
  }

  // epilogue: C/D layout col=lane&15, row=quad*4+r; store only valid slots
#pragma unroll
  for (int im = 0; im < 4; im++) {
#pragma unroll
    for (int r = 0; r < 4; r++) {
      const int slot = m0 + wm + im * 16 + quad * 4 + r;
      if (slot < cnt_e) {
        const float wt = se ? 1.0f : wtl[e * T_TOTAL + slot];
#pragma unroll
        for (int in = 0; in < 4; in++) {
          const int ic = n0 + wn + in * 16 + l16;
          const float g = accg[im][in][r];
          const float u = accu[im][in][r];
          const float v =
              wt * u * 0.5f * g * (1.0f + erff(g * 0.70710678118654752f));
          inter[((size_t)e * T_TOTAL + slot) * IDIM + ic] = (__bf16)v;
        }
      }
    }
  }
}

// ---------------------------------------------------------------------------
// Phase B shared: out[T][H] = inter[8] @ Wd[8]  (plain stores, runs first)
// ---------------------------------------------------------------------------
__global__ __launch_bounds__(256) void k_down_s(const __bf16* __restrict__ iA,
                                                const __bf16* __restrict__ wB,
                                                float* __restrict__ out) {
  __shared__ __bf16 sA[128][32];
  __shared__ __bf16 sB[128][32];
  const int tid = threadIdx.x;
  const int w = tid >> 6, lane = tid & 63;
  const int m0 = blockIdx.x * 128, n0 = blockIdx.y * 128;

  const int off = tid * 16;
  const int r0 = off >> 6, cb = off & 63;
  const int r1 = r0 + 64;

  const char* gA0 = (const char*)iA + (size_t)(m0 + r0) * 1024 + cb;
  const char* gA1 = (const char*)iA + (size_t)(m0 + r1) * 1024 + cb;
  const char* gB0 = (const char*)wB + (size_t)(n0 + r0) * 1024 + cb;
  const char* gB1 = (const char*)wB + (size_t)(n0 + r1) * 1024 + cb;

  char* sA0 = (char*)&sA[0][0] + w * 1024;
  char* sA1 = sA0 + 4096;
  char* sB0 = (char*)&sB[0][0] + w * 1024;
  char* sB1 = sB0 + 4096;

  const int quad = lane >> 4, l16 = lane & 15;
  const int wm = (w & 1) * 64, wn = (w >> 1) * 64;

  f32x4 zero4 = {0.f, 0.f, 0.f, 0.f};
  f32x4 acc[4][4];
#pragma unroll
  for (int im = 0; im < 4; im++)
#pragma unroll
    for (int in = 0; in < 4; in++) acc[im][in] = zero4;

  for (int k = 0; k < IDIM; k += 32) {
    __syncthreads();
    load_lds16(gA0, sA0);
    load_lds16(gA1, sA1);
    load_lds16(gB0, sB0);
    load_lds16(gB1, sB1);
    gA0 += 64; gA1 += 64; gB0 += 64; gB1 += 64;
    __syncthreads();
    bf16x8 af[4], bfr[4];
#pragma unroll
    for (int i = 0; i < 4; i++) {
      af[i] = *(const bf16x8*)&sA[wm + i * 16 + l16][quad * 8];
      bfr[i] = *(const bf16x8*)&sB[wn + i * 16 + l16][quad * 8];
    }
#pragma unroll
    for (int im = 0; im < 4; im++)
#pragma unroll
      for (int in = 0; in < 4; in++)
        acc[im][in] = mfma_bf16(af[im], bfr[in], acc[im][in]);
  }

#pragma unroll
  for (int im = 0; im < 4; im++) {
#pragma unroll
    for (int r = 0; r < 4; r++) {
      const int t = m0 + wm + im * 16 + quad * 4 + r;
#pragma unroll
      for (int in = 0; in < 4; in++)
        out[(size_t)t * HDIM + n0 + wn + in * 16 + l16] = acc[im][in][r];
    }
  }
}

// ---------------------------------------------------------------------------
// Phase B routed: per expert e, gathered GEMM inter[e][0..cnt) @ Wd[e],
// scatter atomic-add into out rows (runs after k_down_s initialized out).
// ---------------------------------------------------------------------------
__global__ __launch_bounds__(256) void k_down_r(const __bf16* __restrict__ inter,
                                                const __bf16* __restrict__ WdT,
                                                const int* __restrict__ tok,
                                                const int* __restrict__ cnt,
                                                float* __restrict__ out) {
  const int e = blockIdx.z;
  const int cnt_e = cnt[e * CNT_STRIDE];
  const int m0 = blockIdx.x * 128;
  if (m0 >= cnt_e) return;

  __shared__ __bf16 sA[128][32];
  __shared__ __bf16 sB[128][32];
  const int tid = threadIdx.x;
  const int w = tid >> 6, lane = tid & 63;
  const int n0 = blockIdx.y * 128;

  const int off = tid * 16;
  const int r0 = off >> 6, cb = off & 63;
  const int r1 = r0 + 64;

  int s0 = m0 + r0; if (s0 > cnt_e - 1) s0 = cnt_e - 1;
  int s1 = m0 + r1; if (s1 > cnt_e - 1) s1 = cnt_e - 1;

  const char* gA0 =
      (const char*)inter + ((size_t)e * T_TOTAL + s0) * 1024 + cb;
  const char* gA1 =
      (const char*)inter + ((size_t)e * T_TOTAL + s1) * 1024 + cb;
  const char* gB0 = (const char*)WdT + ((size_t)e * HDIM + n0 + r0) * 1024 + cb;
  const char* gB1 = (const char*)WdT + ((size_t)e * HDIM + n0 + r1) * 1024 + cb;

  char* sA0 = (char*)&sA[0][0] + w * 1024;
  char* sA1 = sA0 + 4096;
  char* sB0 = (char*)&sB[0][0] + w * 1024;
  char* sB1 = sB0 + 4096;

  const int quad = lane >> 4, l16 = lane & 15;
  const int wm = (w & 1) * 64, wn = (w >> 1) * 64;

  f32x4 zero4 = {0.f, 0.f, 0.f, 0.f};
  f32x4 acc[4][4];
#pragma unroll
  for (int im = 0; im < 4; im++)
#pragma unroll
    for (int in = 0; in < 4; in++) acc[im][in] = zero4;

  for (int k = 0; k < IDIM; k += 32) {
    __syncthreads();
    load_lds16(gA0, sA0);
    load_lds16(gA1, sA1);
    load_lds16(gB0, sB0);
    load_lds16(gB1, sB1);
    gA0 += 64; gA1 += 64; gB0 += 64; gB1 += 64;
    __syncthreads();
    bf16x8 af[4], bfr[4];
#pragma unroll
    for (int i = 0; i < 4; i++) {
      af[i] = *(const bf16x8*)&sA[wm + i * 16 + l16][quad * 8];
      bfr[i] = *(const bf16x8*)&sB[wn + i * 16 + l16][quad * 8];
    }
#pragma unroll
    for (int im = 0; im < 4; im++)
#pragma unroll
      for (int in = 0; in < 4; in++)
        acc[im][in] = mfma_bf16(af[im], bfr[in], acc[im][in]);
  }

#pragma unroll
  for (int im = 0; im < 4; im++) {
#pragma unroll
    for (int r = 0; r < 4; r++) {
      const int slot = m0 + wm + im * 16 + quad * 4 + r;
      if (slot < cnt_e) {
        const int t = tok[e * T_TOTAL + slot];
#pragma unroll
        for (int in = 0; in < 4; in++)
          atomicAdd(&out[(size_t)t * HDIM + n0 + wn + in * 16 + l16],
                    acc[im][in][r]);
      }
    }
  }
}

// ---------------------------------------------------------------------------
extern "C" void kernel_launch(void* const* d_in, const int* in_sizes, int n_in,
                              void* d_out, int out_size, void* d_ws,
                              size_t ws_size, hipStream_t stream) {
  const float* x = (const float*)d_in[0];
  const float* gw = (const float*)d_in[1];
  const float* Wg = (const float*)d_in[2];
  const float* Wu = (const float*)d_in[3];
  const float* Wd = (const float*)d_in[4];
  const float* sWg = (const float*)d_in[5];
  const float* sWu = (const float*)d_in[6];
  const float* sWd = (const float*)d_in[7];
  float* out = (float*)d_out;

  char* ws = (char*)d_ws;
  size_t off = 0;
  auto alloc = [&](size_t n) {
    char* p = ws + off;
    off += (n + 255) & ~(size_t)255;
    return p;
  };
  __bf16* xb = (__bf16*)alloc((size_t)T_TOTAL * HDIM * 2);          // 33.5 MB
  __bf16* WgT = (__bf16*)alloc((size_t)NE * IDIM * HDIM * 2);       // 9.4 MB
  __bf16* WuT = (__bf16*)alloc((size_t)NE * IDIM * HDIM * 2);       // 9.4 MB
  __bf16* WdT = (__bf16*)alloc((size_t)NE * HDIM * IDIM * 2);       // 9.4 MB
  int* tok = (int*)alloc((size_t)8 * T_TOTAL * 4);                  // 512 KB
  float* wtl = (float*)alloc((size_t)8 * T_TOTAL * 4);              // 512 KB
  int* cnt = (int*)alloc(8 * CNT_STRIDE * 4);
  __bf16* inter = (__bf16*)alloc((size_t)NE * T_TOTAL * IDIM * 2);  // 151 MB

  hipMemsetAsync(cnt, 0, 8 * CNT_STRIDE * 4, stream);

  k_gate<<<dim3(T_TOTAL / 64), dim3(256), 0, stream>>>(x, gw, xb, tok, wtl,
                                                       cnt);
  // Wg [8][H][I] + sWg [H][I] -> WgT [9][I][H]
  k_transpose<<<dim3(IDIM / 32, HDIM / 32, NE), dim3(256), 0, stream>>>(
      Wg, sWg, WgT, HDIM, IDIM);
  k_transpose<<<dim3(IDIM / 32, HDIM / 32, NE), dim3(256), 0, stream>>>(
      Wu, sWu, WuT, HDIM, IDIM);
  // Wd [8][I][H] + sWd [I][H] -> WdT [9][H][I]
  k_transpose<<<dim3(HDIM / 32, IDIM / 32, NE), dim3(256), 0, stream>>>(
      Wd, sWd, WdT, IDIM, HDIM);

  // Phase A: grid covers worst case (any expert up to T tokens); early-exit.
  k_gu<<<dim3(T_TOTAL / 128, IDIM / 128, NE), dim3(256), 0, stream>>>(
      xb, WgT, WuT, tok, wtl, cnt, inter);

  // Phase B: shared expert first (plain stores initialize out) ...
  k_down_s<<<dim3(T_TOTAL / 128, HDIM / 128), dim3(256), 0, stream>>>(
      inter + (size_t)8 * T_TOTAL * IDIM, WdT + (size_t)8 * HDIM * IDIM, out);
  // ... then routed experts atomic-add on top.
  k_down_r<<<dim3(T_TOTAL / 128, HDIM / 128, 8), dim3(256), 0, stream>>>(
      inter, WdT, tok, cnt, out);
}

// Round 4
// 477.008 us; speedup vs baseline: 2.3686x; 1.5158x over previous
//
#include <hip/hip_runtime.h>
#include <hip/hip_bf16.h>
#include <math.h>

// ---------------------------------------------------------------------------
// DeepseekV2 MoE: T=16384 tokens, H=1024, E=8 routed (top-2) + 1 shared, I=512
// Round 4: phase-A restructure.
//  - Fused GU weights: B operand rows interleave 16 G-cols / 16 U-cols, so one
//    GEMM (16 acc frags = 64 AGPR, not 128) produces both; G_i,U_i in same lane.
//  - XOR swizzle (chunk ^ row&7) on LDS K-chunks, applied at the global source
//    address: conflict-free ds_read_b128, wave-uniform LDS dest preserved.
//  - BK=64: half the barrier/vmcnt drains, 32 MFMA per barrier pair.
//  Same treatment for k_down_s / k_down_r.
// ---------------------------------------------------------------------------

#define T_TOTAL 16384
#define HDIM 1024
#define IDIM 512
#define NE 9  // 8 routed + 1 shared (expert index 8)
#define CNT_STRIDE 16

typedef __bf16 bf16x8 __attribute__((ext_vector_type(8)));
typedef float f32x4 __attribute__((ext_vector_type(4)));

typedef __attribute__((address_space(1))) void gvoid_t;
typedef __attribute__((address_space(3))) void lvoid_t;

__device__ __forceinline__ void load_lds16(const void* g, void* l) {
  // 16B/lane; LDS dest = wave-uniform base + lane*16 (global src may scatter)
  __builtin_amdgcn_global_load_lds((const gvoid_t*)g, (lvoid_t*)l, 16, 0, 0);
}

__device__ __forceinline__ f32x4 mfma_bf16(bf16x8 a, bf16x8 b, f32x4 c) {
  return __builtin_amdgcn_mfma_f32_16x16x32_bf16(a, b, c, 0, 0, 0);
}

// ---------------------------------------------------------------------------
// Gate (unchanged from round 3): block-aggregated slot assignment.
// ---------------------------------------------------------------------------
__global__ __launch_bounds__(256) void k_gate(const float* __restrict__ x,
                                              const float* __restrict__ gw,
                                              __bf16* __restrict__ xb,
                                              int* __restrict__ tok,
                                              float* __restrict__ wtl,
                                              int* __restrict__ cnt) {
  __shared__ int s_eid[64][2];
  __shared__ float s_wt[64][2];
  __shared__ int s_rank[64][2];
  __shared__ int lcnt[8];
  __shared__ int lbase[8];
  const int wv = threadIdx.x >> 6, lane = threadIdx.x & 63;
  if (threadIdx.x < 8) lcnt[threadIdx.x] = 0;
  __syncthreads();

  for (int i = 0; i < 16; i++) {
    const int tl = wv * 16 + i;
    const int t = blockIdx.x * 64 + tl;
    const float* xr = x + (size_t)t * HDIM + lane * 16;
    float4 xv[4];
#pragma unroll
    for (int j = 0; j < 4; j++) xv[j] = ((const float4*)xr)[j];

    bf16x8 v0, v1;
#pragma unroll
    for (int j = 0; j < 8; j++) v0[j] = (__bf16)((const float*)xv)[j];
#pragma unroll
    for (int j = 0; j < 8; j++) v1[j] = (__bf16)((const float*)xv)[j + 8];
    bf16x8* xbo = (bf16x8*)(xb + (size_t)t * HDIM + lane * 16);
    xbo[0] = v0;
    xbo[1] = v1;

    float acc[8];
#pragma unroll
    for (int e = 0; e < 8; e++) {
      const float4* gp = (const float4*)(gw + e * HDIM + lane * 16);
      float s = 0.f;
#pragma unroll
      for (int j = 0; j < 4; j++) {
        float4 g = gp[j];
        s += xv[j].x * g.x + xv[j].y * g.y + xv[j].z * g.z + xv[j].w * g.w;
      }
      acc[e] = s;
    }
#pragma unroll
    for (int d = 32; d >= 1; d >>= 1) {
#pragma unroll
      for (int e = 0; e < 8; e++) acc[e] += __shfl_xor(acc[e], d, 64);
    }
    if (lane == 0) {
      float mx = acc[0];
#pragma unroll
      for (int e = 1; e < 8; e++) mx = fmaxf(mx, acc[e]);
      float p[8], Z = 0.f;
#pragma unroll
      for (int e = 0; e < 8; e++) {
        p[e] = expf(acc[e] - mx);
        Z += p[e];
      }
#pragma unroll
      for (int e = 0; e < 8; e++) p[e] /= Z;
      int i1 = 0;
#pragma unroll
      for (int e = 1; e < 8; e++)
        if (p[e] > p[i1]) i1 = e;
      int i2 = (i1 == 0) ? 1 : 0;
#pragma unroll
      for (int e = 0; e < 8; e++)
        if (e != i1 && p[e] > p[i2]) i2 = e;
      const float s12 = p[i1] + p[i2] + 1e-20f;
      s_eid[tl][0] = i1;
      s_eid[tl][1] = i2;
      s_wt[tl][0] = p[i1] / s12;
      s_wt[tl][1] = p[i2] / s12;
    }
  }
  __syncthreads();

  if (threadIdx.x < 64) {
    s_rank[threadIdx.x][0] = atomicAdd(&lcnt[s_eid[threadIdx.x][0]], 1);
    s_rank[threadIdx.x][1] = atomicAdd(&lcnt[s_eid[threadIdx.x][1]], 1);
  }
  __syncthreads();
  if (threadIdx.x < 8)
    lbase[threadIdx.x] =
        atomicAdd(&cnt[threadIdx.x * CNT_STRIDE], lcnt[threadIdx.x]);
  __syncthreads();
  if (threadIdx.x < 64) {
    const int t = blockIdx.x * 64 + threadIdx.x;
#pragma unroll
    for (int j = 0; j < 2; j++) {
      const int e = s_eid[threadIdx.x][j];
      const int slot = lbase[e] + s_rank[threadIdx.x][j];
      tok[e * T_TOTAL + slot] = t;
      wtl[e * T_TOTAL + slot] = s_wt[threadIdx.x][j];
    }
  }
}

// ---------------------------------------------------------------------------
// Plain transpose+cast (for Wd): src fp32 [R][C] -> out bf16 [b][C][R]
// ---------------------------------------------------------------------------
__global__ __launch_bounds__(256) void k_transpose(const float* __restrict__ w8,
                                                   const float* __restrict__ w1,
                                                   __bf16* __restrict__ out,
                                                   int R, int C) {
  __shared__ float tile[32][33];
  const int b = blockIdx.z;
  const float* src = (b < 8) ? (w8 + (size_t)b * R * C) : w1;
  const int c0 = blockIdx.x * 32, r0 = blockIdx.y * 32;
  const int tx = threadIdx.x & 31, ty = threadIdx.x >> 5;
#pragma unroll
  for (int i = 0; i < 4; i++)
    tile[ty + i * 8][tx] = src[(size_t)(r0 + ty + i * 8) * C + c0 + tx];
  __syncthreads();
#pragma unroll
  for (int i = 0; i < 4; i++)
    out[(size_t)b * R * C + (size_t)(c0 + ty + i * 8) * R + r0 + tx] =
        (__bf16)tile[tx][ty + i * 8];
}

// ---------------------------------------------------------------------------
// Fused-GU transpose: src fp32 [b][1024 h][512 i] -> Wfu bf16 [b][1024 f][1024 h]
// fused row f(i) = 2*(i & ~15) + (i & 15) + u16off  (u16off: 0 for G, 16 for U)
// => rows [32g..32g+15] = G cols [16g..16g+15], rows [32g+16..+31] = U same.
// ---------------------------------------------------------------------------
__global__ __launch_bounds__(256) void k_transpose_fuse(
    const float* __restrict__ w8, const float* __restrict__ w1,
    __bf16* __restrict__ out, int u16off) {
  __shared__ float tile[32][33];
  const int b = blockIdx.z;
  const float* src = (b < 8) ? (w8 + (size_t)b * HDIM * IDIM) : w1;
  const int c0 = blockIdx.x * 32, r0 = blockIdx.y * 32;  // c=i, r=h
  const int tx = threadIdx.x & 31, ty = threadIdx.x >> 5;
#pragma unroll
  for (int i = 0; i < 4; i++)
    tile[ty + i * 8][tx] = src[(size_t)(r0 + ty + i * 8) * IDIM + c0 + tx];
  __syncthreads();
#pragma unroll
  for (int i = 0; i < 4; i++) {
    const int ic = c0 + ty + i * 8;
    const int f = 2 * (ic & ~15) + (ic & 15) + u16off;
    out[(size_t)b * 1024 * HDIM + (size_t)f * HDIM + r0 + tx] =
        (__bf16)tile[tx][ty + i * 8];
  }
}

// ---------------------------------------------------------------------------
// Phase A (sparse, fused): one GEMM [slots x 128 fused cols], K=H.
// acc[im][2p]=G, acc[im][2p+1]=U for i-col = (n0+wn)/2 + p*16 + l16.
// BK=64, XOR-swizzled LDS, 2 staging streams.
// ---------------------------------------------------------------------------
__global__ __launch_bounds__(256, 2) void k_gu(
    const __bf16* __restrict__ xb, const __bf16* __restrict__ Wfu,
    const int* __restrict__ tok, const float* __restrict__ wtl,
    const int* __restrict__ cnt, __bf16* __restrict__ inter) {
  const int e = blockIdx.z;
  const bool se = (e == 8);
  const int cnt_e = se ? T_TOTAL : cnt[e * CNT_STRIDE];
  const int m0 = blockIdx.x * 128;
  if (m0 >= cnt_e) return;  // uniform early-exit before any barrier

  __shared__ __bf16 sA[128][64];
  __shared__ __bf16 sB[128][64];
  const int tid = threadIdx.x, w = tid >> 6, lane = tid & 63;
  const int n0 = blockIdx.y * 128;  // fused-row base (0..896)
  const int quad = lane >> 4, l16 = lane & 15;
  const int wm = (w & 1) * 64, wn = (w >> 1) * 64;

  // staging: 256 thr x 16B = 4KB/shot = 32 rows of 128B; 4 shots per buffer
  const int sr = tid >> 3;                    // row within shot
  const int scs = ((tid & 7) ^ (sr & 7)) * 8; // swizzled source offset (elems)
  const __bf16* ap[4];
  const __bf16* bp[4];
#pragma unroll
  for (int sh = 0; sh < 4; sh++) {
    int s = m0 + sh * 32 + sr;
    if (s > cnt_e - 1) s = cnt_e - 1;
    const int t = se ? s : tok[e * T_TOTAL + s];
    ap[sh] = xb + (size_t)t * HDIM + scs;
    bp[sh] = Wfu + ((size_t)e * 1024 + n0 + sh * 32 + sr) * HDIM + scs;
  }
  char* const la = (char*)sA + w * 1024;  // +lane*16 implicit in global_load_lds
  char* const lb = (char*)sB + w * 1024;

  f32x4 acc[4][4];
#pragma unroll
  for (int im = 0; im < 4; im++)
#pragma unroll
    for (int in = 0; in < 4; in++) acc[im][in] = {0.f, 0.f, 0.f, 0.f};

  for (int k = 0; k < HDIM; k += 64) {
    __syncthreads();
#pragma unroll
    for (int sh = 0; sh < 4; sh++) {
      load_lds16(ap[sh], la + sh * 4096);
      load_lds16(bp[sh], lb + sh * 4096);
      ap[sh] += 64;
      bp[sh] += 64;
    }
    __syncthreads();
#pragma unroll
    for (int kh = 0; kh < 2; kh++) {
      bf16x8 af[4], bfr[4];
#pragma unroll
      for (int i = 0; i < 4; i++) {
        const int ra = wm + i * 16 + l16;
        af[i] = *(const bf16x8*)((const char*)sA + ra * 128 +
                                 ((kh * 4 + quad) ^ (ra & 7)) * 16);
        const int rb = wn + i * 16 + l16;
        bfr[i] = *(const bf16x8*)((const char*)sB + rb * 128 +
                                  ((kh * 4 + quad) ^ (rb & 7)) * 16);
      }
#pragma unroll
      for (int im = 0; im < 4; im++)
#pragma unroll
        for (int in = 0; in < 4; in++)
          acc[im][in] = mfma_bf16(af[im], bfr[in], acc[im][in]);
    }
  }

  // epilogue: C/D col=lane&15, row=quad*4+r; G/U pairs in even/odd n-frags
#pragma unroll
  for (int im = 0; im < 4; im++) {
#pragma unroll
    for (int r = 0; r < 4; r++) {
      const int slot = m0 + wm + im * 16 + quad * 4 + r;
      if (slot < cnt_e) {
        const float wt = se ? 1.0f : wtl[e * T_TOTAL + slot];
        __bf16* op =
            inter + ((size_t)e * T_TOTAL + slot) * IDIM + ((n0 + wn) >> 1) + l16;
#pragma unroll
        for (int p = 0; p < 2; p++) {
          const float g = acc[im][2 * p][r];
          const float u = acc[im][2 * p + 1][r];
          const float v =
              wt * u * 0.5f * g * (1.0f + erff(g * 0.70710678118654752f));
          op[p * 16] = (__bf16)v;
        }
      }
    }
  }
}

// ---------------------------------------------------------------------------
// Phase B shared: out[T][H] = inter[8] @ Wd[8]  (plain stores, runs first)
// BK=64, swizzled.
// ---------------------------------------------------------------------------
__global__ __launch_bounds__(256, 2) void k_down_s(const __bf16* __restrict__ iA,
                                                   const __bf16* __restrict__ wB,
                                                   float* __restrict__ out) {
  __shared__ __bf16 sA[128][64];
  __shared__ __bf16 sB[128][64];
  const int tid = threadIdx.x, w = tid >> 6, lane = tid & 63;
  const int m0 = blockIdx.x * 128, n0 = blockIdx.y * 128;
  const int quad = lane >> 4, l16 = lane & 15;
  const int wm = (w & 1) * 64, wn = (w >> 1) * 64;

  const int sr = tid >> 3;
  const int scs = ((tid & 7) ^ (sr & 7)) * 8;
  const __bf16* ap[4];
  const __bf16* bp[4];
#pragma unroll
  for (int sh = 0; sh < 4; sh++) {
    ap[sh] = iA + (size_t)(m0 + sh * 32 + sr) * IDIM + scs;
    bp[sh] = wB + (size_t)(n0 + sh * 32 + sr) * IDIM + scs;
  }
  char* const la = (char*)sA + w * 1024;
  char* const lb = (char*)sB + w * 1024;

  f32x4 acc[4][4];
#pragma unroll
  for (int im = 0; im < 4; im++)
#pragma unroll
    for (int in = 0; in < 4; in++) acc[im][in] = {0.f, 0.f, 0.f, 0.f};

  for (int k = 0; k < IDIM; k += 64) {
    __syncthreads();
#pragma unroll
    for (int sh = 0; sh < 4; sh++) {
      load_lds16(ap[sh], la + sh * 4096);
      load_lds16(bp[sh], lb + sh * 4096);
      ap[sh] += 64;
      bp[sh] += 64;
    }
    __syncthreads();
#pragma unroll
    for (int kh = 0; kh < 2; kh++) {
      bf16x8 af[4], bfr[4];
#pragma unroll
      for (int i = 0; i < 4; i++) {
        const int ra = wm + i * 16 + l16;
        af[i] = *(const bf16x8*)((const char*)sA + ra * 128 +
                                 ((kh * 4 + quad) ^ (ra & 7)) * 16);
        const int rb = wn + i * 16 + l16;
        bfr[i] = *(const bf16x8*)((const char*)sB + rb * 128 +
                                  ((kh * 4 + quad) ^ (rb & 7)) * 16);
      }
#pragma unroll
      for (int im = 0; im < 4; im++)
#pragma unroll
        for (int in = 0; in < 4; in++)
          acc[im][in] = mfma_bf16(af[im], bfr[in], acc[im][in]);
    }
  }

#pragma unroll
  for (int im = 0; im < 4; im++) {
#pragma unroll
    for (int r = 0; r < 4; r++) {
      const int t = m0 + wm + im * 16 + quad * 4 + r;
#pragma unroll
      for (int in = 0; in < 4; in++)
        out[(size_t)t * HDIM + n0 + wn + in * 16 + l16] = acc[im][in][r];
    }
  }
}

// ---------------------------------------------------------------------------
// Phase B routed: per expert e, gathered GEMM inter[e][0..cnt) @ Wd[e],
// atomic scatter-add into out (after k_down_s initialized it). BK=64, swizzled.
// ---------------------------------------------------------------------------
__global__ __launch_bounds__(256, 2) void k_down_r(
    const __bf16* __restrict__ inter, const __bf16* __restrict__ WdT,
    const int* __restrict__ tok, const int* __restrict__ cnt,
    float* __restrict__ out) {
  const int e = blockIdx.z;
  const int cnt_e = cnt[e * CNT_STRIDE];
  const int m0 = blockIdx.x * 128;
  if (m0 >= cnt_e) return;

  __shared__ __bf16 sA[128][64];
  __shared__ __bf16 sB[128][64];
  const int tid = threadIdx.x, w = tid >> 6, lane = tid & 63;
  const int n0 = blockIdx.y * 128;
  const int quad = lane >> 4, l16 = lane & 15;
  const int wm = (w & 1) * 64, wn = (w >> 1) * 64;

  const int sr = tid >> 3;
  const int scs = ((tid & 7) ^ (sr & 7)) * 8;
  const __bf16* ap[4];
  const __bf16* bp[4];
#pragma unroll
  for (int sh = 0; sh < 4; sh++) {
    int s = m0 + sh * 32 + sr;
    if (s > cnt_e - 1) s = cnt_e - 1;
    ap[sh] = inter + ((size_t)e * T_TOTAL + s) * IDIM + scs;
    bp[sh] = WdT + ((size_t)e * HDIM + n0 + sh * 32 + sr) * IDIM + scs;
  }
  char* const la = (char*)sA + w * 1024;
  char* const lb = (char*)sB + w * 1024;

  f32x4 acc[4][4];
#pragma unroll
  for (int im = 0; im < 4; im++)
#pragma unroll
    for (int in = 0; in < 4; in++) acc[im][in] = {0.f, 0.f, 0.f, 0.f};

  for (int k = 0; k < IDIM; k += 64) {
    __syncthreads();
#pragma unroll
    for (int sh = 0; sh < 4; sh++) {
      load_lds16(ap[sh], la + sh * 4096);
      load_lds16(bp[sh], lb + sh * 4096);
      ap[sh] += 64;
      bp[sh] += 64;
    }
    __syncthreads();
#pragma unroll
    for (int kh = 0; kh < 2; kh++) {
      bf16x8 af[4], bfr[4];
#pragma unroll
      for (int i = 0; i < 4; i++) {
        const int ra = wm + i * 16 + l16;
        af[i] = *(const bf16x8*)((const char*)sA + ra * 128 +
                                 ((kh * 4 + quad) ^ (ra & 7)) * 16);
        const int rb = wn + i * 16 + l16;
        bfr[i] = *(const bf16x8*)((const char*)sB + rb * 128 +
                                  ((kh * 4 + quad) ^ (rb & 7)) * 16);
      }
#pragma unroll
      for (int im = 0; im < 4; im++)
#pragma unroll
        for (int in = 0; in < 4; in++)
          acc[im][in] = mfma_bf16(af[im], bfr[in], acc[im][in]);
    }
  }

#pragma unroll
  for (int im = 0; im < 4; im++) {
#pragma unroll
    for (int r = 0; r < 4; r++) {
      const int slot = m0 + wm + im * 16 + quad * 4 + r;
      if (slot < cnt_e) {
        const int t = tok[e * T_TOTAL + slot];
#pragma unroll
        for (int in = 0; in < 4; in++)
          atomicAdd(&out[(size_t)t * HDIM + n0 + wn + in * 16 + l16],
                    acc[im][in][r]);
      }
    }
  }
}

// ---------------------------------------------------------------------------
extern "C" void kernel_launch(void* const* d_in, const int* in_sizes, int n_in,
                              void* d_out, int out_size, void* d_ws,
                              size_t ws_size, hipStream_t stream) {
  const float* x = (const float*)d_in[0];
  const float* gw = (const float*)d_in[1];
  const float* Wg = (const float*)d_in[2];
  const float* Wu = (const float*)d_in[3];
  const float* Wd = (const float*)d_in[4];
  const float* sWg = (const float*)d_in[5];
  const float* sWu = (const float*)d_in[6];
  const float* sWd = (const float*)d_in[7];
  float* out = (float*)d_out;

  char* ws = (char*)d_ws;
  size_t off = 0;
  auto alloc = [&](size_t n) {
    char* p = ws + off;
    off += (n + 255) & ~(size_t)255;
    return p;
  };
  __bf16* xb = (__bf16*)alloc((size_t)T_TOTAL * HDIM * 2);          // 33.5 MB
  __bf16* Wfu = (__bf16*)alloc((size_t)NE * 1024 * HDIM * 2);       // 18.9 MB
  __bf16* WdT = (__bf16*)alloc((size_t)NE * HDIM * IDIM * 2);       // 9.4 MB
  int* tok = (int*)alloc((size_t)8 * T_TOTAL * 4);                  // 512 KB
  float* wtl = (float*)alloc((size_t)8 * T_TOTAL * 4);              // 512 KB
  int* cnt = (int*)alloc(8 * CNT_STRIDE * 4);
  __bf16* inter = (__bf16*)alloc((size_t)NE * T_TOTAL * IDIM * 2);  // 151 MB

  hipMemsetAsync(cnt, 0, 8 * CNT_STRIDE * 4, stream);

  k_gate<<<dim3(T_TOTAL / 64), dim3(256), 0, stream>>>(x, gw, xb, tok, wtl,
                                                       cnt);
  // Wg/sWg -> fused rows +0 (G), Wu/sWu -> fused rows +16 (U)
  k_transpose_fuse<<<dim3(IDIM / 32, HDIM / 32, NE), dim3(256), 0, stream>>>(
      Wg, sWg, Wfu, 0);
  k_transpose_fuse<<<dim3(IDIM / 32, HDIM / 32, NE), dim3(256), 0, stream>>>(
      Wu, sWu, Wfu, 16);
  // Wd [8][I][H] + sWd [I][H] -> WdT [9][H][I]
  k_transpose<<<dim3(HDIM / 32, IDIM / 32, NE), dim3(256), 0, stream>>>(
      Wd, sWd, WdT, IDIM, HDIM);

  // Phase A: fused GU, N = 1024 fused rows -> y=8; worst-case x grid, early-exit.
  k_gu<<<dim3(T_TOTAL / 128, 1024 / 128, NE), dim3(256), 0, stream>>>(
      xb, Wfu, tok, wtl, cnt, inter);

  // Phase B: shared expert first (plain stores initialize out) ...
  k_down_s<<<dim3(T_TOTAL / 128, HDIM / 128), dim3(256), 0, stream>>>(
      inter + (size_t)8 * T_TOTAL * IDIM, WdT + (size_t)8 * HDIM * IDIM, out);
  // ... then routed experts atomic-add on top.
  k_down_r<<<dim3(T_TOTAL / 128, HDIM / 128, 8), dim3(256), 0, stream>>>(
      inter, WdT, tok, cnt, out);
}